// Round 3
// baseline (3870.852 us; speedup 1.0000x reference)
//
#include <hip/hip_runtime.h>
#include <math.h>

// Problem constants (match reference)
#define BT   4096      // B*T tokens
#define DIM  512       // D
#define NE   16        // experts
#define TOPK 4
#define HID  2048      // H = 4*D
#define NVIEW 2
#define HSPLIT 4       // split H into chunks of 512
#define HS   (HID/HSPLIT)   // 512

// GEMM tiling: 128x128 tile, 256 threads, 8x8 microtile, BK=16.
#define BM 128
#define BN 128
#define BKT 16

__device__ __forceinline__ float gelu_exact(float x) {
    return 0.5f * x * (1.0f + erff(x * 0.70710678118654752f));
}

// MODE 0: C = A@B (+bias), direct rows          (proj / router)
// MODE 1: hid = gelu(gather(h)@w1[e] + b1[e])   (expert up-proj, H-split)
// MODE 2: pout (=|+=) hid@w2[e] (+b2[e])        (expert down-proj, K-split accum)
template<int MODE>
__global__ __launch_bounds__(256)
void gemm_k(const float* __restrict__ A, const float* __restrict__ Bbase,
            const float* __restrict__ bias, float* __restrict__ C,
            int N, int Kdim, int lda, int ldb, int ldc,
            long strideB, int bias_ld,
            const int* __restrict__ offsets, const int* __restrict__ jobs,
            const int* __restrict__ jobCount, const int* __restrict__ pair_token,
            int accumulate)
{
    int m0, nrows = 0, rowbase = 0;
    const float* Bp;
    const float* biasp = bias;
    if (MODE == 0) {
        m0 = blockIdx.x * BM;
        Bp = Bbase;
    } else {
        int job = blockIdx.x;
        if (job >= *jobCount) return;      // block-uniform exit, before any barrier
        int e = jobs[2*job];
        m0     = jobs[2*job+1];            // row base within this expert
        int off = offsets[e];
        nrows   = offsets[e+1] - off;      // pairs routed to expert e (this chunk)
        rowbase = off;                     // chunk-local slot base
        Bp = Bbase + (long)e * strideB;
        if (bias) biasp = bias + (long)e * bias_ld;
    }
    const int n0 = blockIdx.y * BN;

    __shared__ float As[BKT][BM];
    __shared__ float Bs[BKT][BN];

    const int tid = threadIdx.x;
    const int tx = tid & 15;       // 0..15 -> col*8
    const int ty = tid >> 4;       // 0..15 -> row*8

    // global-load mapping
    const int ar0 = tid >> 2;            // 0..63  (rows ar0, ar0+64)
    const int akg = (tid & 3) * 4;       // k offset 0/4/8/12
    const int kb0 = tid >> 5;            // 0..7   (B rows kb0, kb0+8)
    const int bc  = (tid & 31) * 4;      // 0..124

    // Resolve the two A row pointers once (gather + clamp for ragged tiles)
    const float* Arp0; const float* Arp1;
    {
        int r0 = m0 + ar0, r1 = m0 + ar0 + 64;
        if (MODE != 0) {
            if (r0 >= nrows) r0 = nrows - 1;   // clamp: load valid row, store guarded
            if (r1 >= nrows) r1 = nrows - 1;
        }
        if (MODE == 1) {
            Arp0 = A + (long)pair_token[rowbase + r0] * lda;  // global token row of h
            Arp1 = A + (long)pair_token[rowbase + r1] * lda;
        } else if (MODE == 2) {
            Arp0 = A + (long)(rowbase + r0) * lda;            // chunk-local hid row
            Arp1 = A + (long)(rowbase + r1) * lda;
        } else {
            Arp0 = A + (long)r0 * lda;
            Arp1 = A + (long)r1 * lda;
        }
    }

    float acc[8][8] = {};

    for (int kt = 0; kt < Kdim; kt += BKT) {
        float4 a0 = *(const float4*)(Arp0 + kt + akg);
        float4 a1 = *(const float4*)(Arp1 + kt + akg);
        float4 b0 = *(const float4*)(Bp + (long)(kt + kb0    ) * ldb + n0 + bc);
        float4 b1 = *(const float4*)(Bp + (long)(kt + kb0 + 8) * ldb + n0 + bc);
        __syncthreads();   // WAR: previous iter's LDS reads done before overwrite
        As[akg+0][ar0] = a0.x; As[akg+1][ar0] = a0.y;
        As[akg+2][ar0] = a0.z; As[akg+3][ar0] = a0.w;
        As[akg+0][ar0+64] = a1.x; As[akg+1][ar0+64] = a1.y;
        As[akg+2][ar0+64] = a1.z; As[akg+3][ar0+64] = a1.w;
        *(float4*)&Bs[kb0  ][bc] = b0;
        *(float4*)&Bs[kb0+8][bc] = b1;
        __syncthreads();
        #pragma unroll
        for (int k = 0; k < BKT; ++k) {
            float ar[8], br[8];
            *(float4*)&ar[0] = *(const float4*)&As[k][ty*8];
            *(float4*)&ar[4] = *(const float4*)&As[k][ty*8+4];
            *(float4*)&br[0] = *(const float4*)&Bs[k][tx*8];
            *(float4*)&br[4] = *(const float4*)&Bs[k][tx*8+4];
            #pragma unroll
            for (int i = 0; i < 8; ++i)
                #pragma unroll
                for (int j = 0; j < 8; ++j)
                    acc[i][j] = fmaf(ar[i], br[j], acc[i][j]);
        }
    }

    // epilogue
    float bv[8];
    #pragma unroll
    for (int j = 0; j < 8; ++j) {
        if (MODE == 1 || (MODE == 0 && bias) || (MODE == 2 && !accumulate))
            bv[j] = biasp[n0 + tx*8 + j];
        else
            bv[j] = 0.f;
    }
    #pragma unroll
    for (int i = 0; i < 8; ++i) {
        int gr = m0 + ty*8 + i;
        if (MODE != 0 && gr >= nrows) break;   // ragged tail rows
        long crow = (MODE == 0) ? (long)gr : (long)(rowbase + gr);
        float* Cr = C + crow * ldc + n0 + tx*8;
        float v[8];
        #pragma unroll
        for (int j = 0; j < 8; ++j) {
            float x = acc[i][j] + bv[j];
            if (MODE == 1) x = gelu_exact(x);
            v[j] = x;
        }
        if (MODE == 2 && accumulate) {
            float4 c0 = *(float4*)&Cr[0];
            float4 c1 = *(float4*)&Cr[4];
            v[0]+=c0.x; v[1]+=c0.y; v[2]+=c0.z; v[3]+=c0.w;
            v[4]+=c1.x; v[5]+=c1.y; v[6]+=c1.z; v[7]+=c1.w;
        }
        *(float4*)&Cr[0] = make_float4(v[0],v[1],v[2],v[3]);
        *(float4*)&Cr[4] = make_float4(v[4],v[5],v[6],v[7]);
    }
}

// One wave per token: Laplace distances to 16 keys, top-4 (ties -> lowest
// index, matching jax.lax.top_k), softmax over top-4. No counting here.
__global__ __launch_bounds__(256)
void gate_k(const float* __restrict__ r, const float* __restrict__ keys,
            int* __restrict__ topidx, float* __restrict__ gates)
{
    const int wave = threadIdx.x >> 6;
    const int lane = threadIdx.x & 63;
    const int t = blockIdx.x * 4 + wave;

    float rv[8];
    const float* rrow = r + (long)t * DIM;
    #pragma unroll
    for (int j = 0; j < 8; ++j) rv[j] = rrow[lane + j*64];

    float logit[NE];
    #pragma unroll
    for (int e = 0; e < NE; ++e) {
        const float* krow = keys + e * DIM;
        float s = 0.f;
        #pragma unroll
        for (int j = 0; j < 8; ++j) {
            float d = rv[j] - krow[lane + j*64];
            s = fmaf(d, d, s);
        }
        #pragma unroll
        for (int o = 32; o > 0; o >>= 1) s += __shfl_xor(s, o, 64);
        logit[e] = -sqrtf(fmaxf(s, 0.f));
    }
    // top-4, strict > => lowest index wins ties (jax.lax.top_k semantics)
    int sel[TOPK]; float selv[TOPK];
    unsigned mask = 0;
    #pragma unroll
    for (int k = 0; k < TOPK; ++k) {
        float best = -INFINITY; int bi = 0;
        #pragma unroll
        for (int e = 0; e < NE; ++e) {
            if (mask & (1u << e)) continue;
            if (logit[e] > best) { best = logit[e]; bi = e; }
        }
        mask |= 1u << bi; sel[k] = bi; selv[k] = best;
    }
    float m = selv[0], se = 0.f, ex[TOPK];
    #pragma unroll
    for (int k = 0; k < TOPK; ++k) { ex[k] = expf(selv[k] - m); se += ex[k]; }
    if (lane == 0) {
        #pragma unroll
        for (int k = 0; k < TOPK; ++k) {
            topidx[t*TOPK + k] = sel[k];
            gates [t*TOPK + k] = ex[k] / se;
        }
    }
}

// Per-chunk expert histogram over (token,k) pairs [base4, base4+n4).
__global__ void count_k(const int* __restrict__ topidx, int base4, int n4,
                        int* __restrict__ counts)
{
    int i = blockIdx.x * blockDim.x + threadIdx.x;
    if (i < n4) atomicAdd(&counts[topidx[base4 + i]], 1);
}

// Single thread: exclusive scan of counts -> offsets, build (expert,m0) jobs.
__global__ void scan_jobs_k(const int* __restrict__ counts, int* __restrict__ offsets,
                            int* __restrict__ jobs, int* __restrict__ jobCount)
{
    int off = 0, nj = 0;
    for (int e = 0; e < NE; ++e) {
        offsets[e] = off;
        int n = counts[e];
        for (int m0 = 0; m0 < n; m0 += BM) { jobs[2*nj] = e; jobs[2*nj+1] = m0; ++nj; }
        off += n;
    }
    offsets[NE] = off;   // == n4 for this chunk
    *jobCount = nj;
}

// Assign each chunk-local (token,k) a contiguous slot within its expert range.
__global__ void assign_k(const int* __restrict__ topidx, int base4, int baseTok, int n4,
                         const int* __restrict__ offsets, int* __restrict__ cursors,
                         int* __restrict__ pair_token, int* __restrict__ token_slot)
{
    int i = blockIdx.x * blockDim.x + threadIdx.x;
    if (i >= n4) return;
    int tl = i >> 2;                       // chunk-local token
    int e = topidx[base4 + i];
    int slot = offsets[e] + atomicAdd(&cursors[e], 1);
    pair_token[slot] = baseTok + tl;       // GLOBAL token id (for h gather)
    token_slot[i] = slot;                  // chunk-local slot (for combine)
}

// out[baseTok+tl,:] (=|+=) sum_k gate * pout[slot(tl,k),:]
__global__ __launch_bounds__(128)
void combine_k(const float* __restrict__ pout, const float* __restrict__ gates,
               const int* __restrict__ token_slot, float* __restrict__ out,
               int baseTok, int add)
{
    const int tl = blockIdx.x;
    const int gt = baseTok + tl;
    const int d4 = threadIdx.x;          // 0..127 float4 lanes = 512 floats
    float4 acc = add ? ((const float4*)out)[(long)gt*128 + d4]
                     : make_float4(0.f, 0.f, 0.f, 0.f);
    #pragma unroll
    for (int k = 0; k < TOPK; ++k) {
        int slot = token_slot[tl*TOPK + k];
        float g  = gates[(long)gt*TOPK + k];
        float4 p = ((const float4*)pout)[(long)slot*128 + d4];
        acc.x = fmaf(g, p.x, acc.x); acc.y = fmaf(g, p.y, acc.y);
        acc.z = fmaf(g, p.z, acc.z); acc.w = fmaf(g, p.w, acc.w);
    }
    ((float4*)out)[(long)gt*128 + d4] = acc;
}

extern "C" void kernel_launch(void* const* d_in, const int* in_sizes, int n_in,
                              void* d_out, int out_size, void* d_ws, size_t ws_size,
                              hipStream_t stream)
{
    const float* view[2]  = {(const float*)d_in[0], (const float*)d_in[1]};
    const float* proj_w   = (const float*)d_in[2];
    const float* proj_b   = (const float*)d_in[3];
    const float* router_w = (const float*)d_in[4];
    const float* keys     = (const float*)d_in[5];
    const float* w1       = (const float*)d_in[6];
    const float* b1       = (const float*)d_in[7];
    const float* w2       = (const float*)d_in[8];
    const float* b2       = (const float*)d_in[9];
    float* out = (float*)d_out;

    // ---- ws budget: pick the largest chunk size C that fits ws_size ----
    // layout (floats): h[2M] | chunkA[4C*512] | chunkB[4C*512] | gates[16K]
    //                  | ints: topidx[16K] token_slot[16K] pair_token[16K]
    //                          counts[16] cursors[16] jobCount[1] offsets[17] jobs[320]
    const size_t hF    = (size_t)BT * DIM;                 // 2,097,152 floats
    const size_t metaF = (size_t)BT * TOPK;                // gates
    const size_t metaI = (size_t)BT * TOPK * 3 + 16 + 16 + 1 + (NE + 1) + 320;
    int C = 512;                                           // floor (r-alias needs C>=512)
    {
        const int cand[3] = {2048, 1024, 512};
        for (int ci = 0; ci < 3; ++ci) {
            size_t sC = (size_t)4 * cand[ci] * DIM;        // chunk buffer floats
            size_t needB = 4 * (hF + 2 * sC + metaF + metaI);
            if (needB + (4u << 20) <= ws_size) { C = cand[ci]; break; }
        }
    }
    const size_t sC = (size_t)4 * C * DIM;
    const int chunks = BT / C;
    const int mj = C / 32 + 16;      // grid bound: max jobs per chunk (+1 slack)

    float* h      = (float*)d_ws;
    float* chunkA = h + hF;          // hid_c; also aliases r before chunk loop
    float* chunkB = chunkA + sC;     // pout_c
    float* gates  = chunkB + sC;
    int* topidx     = (int*)(gates + metaF);
    int* token_slot = topidx + BT*TOPK;
    int* pair_token = token_slot + BT*TOPK;
    int* counts     = pair_token + BT*TOPK;  // 16 ints (memset with next 17)
    int* cursors    = counts + NE;           // 16 ints
    int* jobCount   = cursors + NE;          // 1 int   -> 33 total memset
    int* offsets    = jobCount + 1;          // 17
    int* jobs       = offsets + NE + 1;      // 320

    float* r = chunkA;   // 2M floats spanning chunkA(+chunkB); dead before chunk loop

    const long sB1 = (long)DIM * HID;   // w1 expert stride
    const long sB2 = (long)HID * DIM;   // w2 expert stride

    for (int v = 0; v < NVIEW; ++v) {
        dim3 gp(BT/BM, DIM/BN);   // 32 x 4
        // h = x @ proj_w[v] + proj_b[v]
        gemm_k<0><<<gp, 256, 0, stream>>>(view[v], proj_w + (long)v*DIM*DIM,
            proj_b + v*DIM, h, DIM, DIM, DIM, DIM, DIM,
            0, 0, nullptr, nullptr, nullptr, nullptr, 0);
        // r = h @ router_w[v]
        gemm_k<0><<<gp, 256, 0, stream>>>(h, router_w + (long)v*DIM*DIM,
            nullptr, r, DIM, DIM, DIM, DIM, DIM,
            0, 0, nullptr, nullptr, nullptr, nullptr, 0);
        // gates/topidx for all tokens
        gate_k<<<BT/4, 256, 0, stream>>>(r, keys, topidx, gates);

        for (int c = 0; c < chunks; ++c) {
            const int base4 = c * C * TOPK, baseTok = c * C, n4 = C * TOPK;
            (void)hipMemsetAsync(counts, 0, 33 * sizeof(int), stream);
            count_k<<<(n4 + 255)/256, 256, 0, stream>>>(topidx, base4, n4, counts);
            scan_jobs_k<<<1, 1, 0, stream>>>(counts, offsets, jobs, jobCount);
            assign_k<<<(n4 + 255)/256, 256, 0, stream>>>(topidx, base4, baseTok, n4,
                                                         offsets, cursors,
                                                         pair_token, token_slot);
            for (int s = 0; s < HSPLIT; ++s) {
                dim3 ge(mj, HS/BN);   // dead jobs early-exit
                // hid_c = gelu(gather(h) @ w1[e][:, s*HS:(s+1)*HS] + b1[e][s*HS:])
                gemm_k<1><<<ge, 256, 0, stream>>>(h, w1 + s*HS, b1 + s*HS, chunkA,
                    HS, DIM, DIM, HID, HS,
                    sB1, HID, offsets, jobs, jobCount, pair_token, 0);
                // pout_c (=|+=) hid_c @ w2[e][s*HS:(s+1)*HS, :] (+ b2[e] on s==0)
                gemm_k<2><<<dim3(mj, DIM/BN), 256, 0, stream>>>(chunkA,
                    w2 + (long)s*HS*DIM, b2, chunkB,
                    DIM, HS, HS, DIM, DIM,
                    sB2, DIM, offsets, jobs, jobCount, nullptr, (s > 0) ? 1 : 0);
            }
            combine_k<<<C, 128, 0, stream>>>(chunkB, gates, token_slot, out,
                                             baseTok, v);
        }
    }
}

// Round 4
// 1256.170 us; speedup vs baseline: 3.0815x; 3.0815x over previous
//
#include <hip/hip_runtime.h>
#include <math.h>

// Problem constants (match reference)
#define BT   4096      // B*T tokens
#define DIM  512       // D
#define NE   16        // experts
#define TOPK 4
#define HID  2048      // H = 4*D
#define NVIEW 2
#define HSPLIT 2       // split H into chunks of 1024
#define HS   (HID/HSPLIT)   // 1024

#define BM 128         // MFMA tile M (scan_jobs step)

typedef float f4 __attribute__((ext_vector_type(4)));
typedef float f32x4 __attribute__((ext_vector_type(4)));
typedef short s16x8 __attribute__((ext_vector_type(8)));
typedef unsigned short u16x8 __attribute__((ext_vector_type(8)));
typedef unsigned short u16x4 __attribute__((ext_vector_type(4)));

__device__ __forceinline__ unsigned short f2bf(float f) {   // fp32 -> bf16 RNE
    unsigned u = __float_as_uint(f);
    unsigned r = u + 0x7FFFu + ((u >> 16) & 1u);
    return (unsigned short)(r >> 16);
}
__device__ __forceinline__ float gelu_exact(float x) {
    return 0.5f * x * (1.0f + erff(x * 0.70710678118654752f));
}
// 16B-chunk swizzle within a 128B LDS row: bijective, spreads reads 2-way
// and transpose-writes ~4-way across banks.
__device__ __forceinline__ int swz(int r) { return (r ^ (r >> 3)) & 7; }

// ---------------- fp32 64x64 GEMM for proj/router (occupancy fix) ----------
// C[M=BT][DIM] = A[BT][DIM] @ B[DIM][DIM] (+bias); optional bf16 dual-store.
__global__ __launch_bounds__(256)
void gemm0_k(const float* __restrict__ A, const float* __restrict__ B,
             const float* __restrict__ bias, float* __restrict__ C,
             unsigned short* __restrict__ bfout)
{
    const int m0 = blockIdx.x * 64, n0 = blockIdx.y * 64;
    __shared__ float As[16][64];
    __shared__ float Bs[16][64];
    const int tid = threadIdx.x;
    const int tx = tid & 15, ty = tid >> 4;
    const int ar = tid >> 2, ak = (tid & 3) * 4;   // A: row, k-quad
    const int bk = tid >> 4, bn = (tid & 15) * 4;  // B: k-row, n-quad
    const float* Ar = A + (size_t)(m0 + ar) * DIM;

    float acc[4][4] = {};
    for (int kt = 0; kt < DIM; kt += 16) {
        f4 av = *(const f4*)(Ar + kt + ak);
        f4 bv = *(const f4*)(B + (size_t)(kt + bk) * DIM + n0 + bn);
        __syncthreads();
        As[ak+0][ar] = av[0]; As[ak+1][ar] = av[1];
        As[ak+2][ar] = av[2]; As[ak+3][ar] = av[3];
        *(f4*)&Bs[bk][bn] = bv;
        __syncthreads();
        #pragma unroll
        for (int k = 0; k < 16; ++k) {
            f4 a = *(const f4*)&As[k][ty*4];
            f4 b = *(const f4*)&Bs[k][tx*4];
            #pragma unroll
            for (int i = 0; i < 4; ++i)
                #pragma unroll
                for (int j = 0; j < 4; ++j)
                    acc[i][j] = fmaf(a[i], b[j], acc[i][j]);
        }
    }
    #pragma unroll
    for (int i = 0; i < 4; ++i) {
        int gr = m0 + ty*4 + i;
        f4 v;
        #pragma unroll
        for (int j = 0; j < 4; ++j)
            v[j] = acc[i][j] + (bias ? bias[n0 + tx*4 + j] : 0.f);
        *(f4*)(C + (size_t)gr * DIM + n0 + tx*4) = v;
        if (bfout) {
            u16x4 w = { f2bf(v[0]), f2bf(v[1]), f2bf(v[2]), f2bf(v[3]) };
            *(u16x4*)&bfout[(size_t)gr * DIM + n0 + tx*4] = w;
        }
    }
}

// ---------------- bf16 MFMA expert GEMM ------------------------------------
// MODE 1: hid(bf16) = gelu(gather_bf16(h) @ bf16(w1 slice) + b1)   ldc=HS
// MODE 2: pout(f32) (=|+=) hid_bf16 @ bf16(w2 slice) (+b2 if first) ldc=DIM
// Tile 128x128, BK=64, 4 waves (2x2), wave tile 64x64 (4x4 frags of 16x16x32).
template<int MODE>
__global__ __launch_bounds__(256, 2)
void moe_mfma_k(const unsigned short* __restrict__ Ab,  // bf16: h_bf16 / hid_c
                const float* __restrict__ Bg,           // fp32 weight slice base
                const float* __restrict__ biasb,
                void* __restrict__ Cout,
                int Kdim, int lda, int ldb, int ldc, int bias_ld, long strideB,
                const int* __restrict__ offsets, const int* __restrict__ jobs,
                const int* __restrict__ jobCount,
                const int* __restrict__ pair_token, int first)
{
    const int job = blockIdx.x;
    if (job >= *jobCount) return;             // uniform exit before any barrier
    const int e  = jobs[2*job];
    const int m0 = jobs[2*job+1];
    const int rowbase = offsets[e];
    const int nrows   = offsets[e+1] - rowbase;
    const float* Bp    = Bg + (long)e * strideB;
    const float* biasp = biasb + (long)e * bias_ld;
    const int n0 = blockIdx.y * 128;

    __shared__ unsigned short As[128*64];   // [row][64 k] bf16, swizzled 16B chunks
    __shared__ unsigned short Bs[128*64];   // [col][64 k] bf16 (transposed), swizzled

    const int tid = threadIdx.x;

    // --- A row pointer (gathered for MODE1; clamped for ragged tail) ---
    const unsigned short* arow;
    {
        int r = m0 + (tid & 127);
        if (r >= nrows) r = nrows - 1;
        if (MODE == 1) arow = Ab + (size_t)pair_token[rowbase + r] * lda;
        else           arow = Ab + (size_t)(rowbase + r) * lda;
    }
    const int arr = tid & 127;            // LDS A row this thread fills
    const int acs = (tid >> 7) * 4;       // 16B-chunk start (0 or 4)

    // --- B staging cells: cell = (k-quad kq, n-quad nq), 2 cells/thread ---
    const int kq0 = tid >> 5;             // 0..7
    const int nq0 = tid & 31;             // 0..31
    const int kq1 = kq0 + 8;              // 8..15

    // --- fragment geometry ---
    const int lane = tid & 63;
    const int wid  = tid >> 6;
    const int wm = wid >> 1, wn = wid & 1;      // 2x2 wave grid
    const int fr = lane & 15, fq = lane >> 4;   // frag row/col, k-quarter

    f32x4 acc[4][4] = {};
    u16x8 areg[4];
    f4 breg[2][4];

    // preload kt = 0
    #pragma unroll
    for (int c = 0; c < 4; ++c)
        areg[c] = *(const u16x8*)(arow + (acs + c) * 8);
    {
        const float* bs0 = Bp + (size_t)(kq0*4) * ldb + n0 + nq0*4;
        const float* bs1 = Bp + (size_t)(kq1*4) * ldb + n0 + nq0*4;
        #pragma unroll
        for (int j = 0; j < 4; ++j) { breg[0][j] = *(const f4*)(bs0 + j*ldb);
                                      breg[1][j] = *(const f4*)(bs1 + j*ldb); }
    }

    for (int kt = 0; kt < Kdim; kt += 64) {
        __syncthreads();                       // prior iter's LDS reads done
        // write A (already bf16): 4 x ds_write_b128, swizzled
        #pragma unroll
        for (int c = 0; c < 4; ++c) {
            int ch = acs + c;
            *(u16x8*)&As[arr*64 + ((ch ^ swz(arr)) << 3)] = areg[c];
        }
        // write B transposed [n][k]: cvt fp32->bf16, 8 x ds_write_b64, swizzled
        #pragma unroll
        for (int cell = 0; cell < 2; ++cell) {
            int kq = cell ? kq1 : kq0;
            #pragma unroll
            for (int j = 0; j < 4; ++j) {
                int n = nq0*4 + j;
                u16x4 w = { f2bf(breg[cell][0][j]), f2bf(breg[cell][1][j]),
                            f2bf(breg[cell][2][j]), f2bf(breg[cell][3][j]) };
                *(u16x4*)&Bs[n*64 + (((kq>>1) ^ swz(n)) << 3) + ((kq&1) << 2)] = w;
            }
        }
        __syncthreads();
        // prefetch next K-tile into regs (hides HBM latency under MFMA)
        if (kt + 64 < Kdim) {
            #pragma unroll
            for (int c = 0; c < 4; ++c)
                areg[c] = *(const u16x8*)(arow + kt + 64 + (acs + c) * 8);
            const float* bs0 = Bp + (size_t)(kt + 64 + kq0*4) * ldb + n0 + nq0*4;
            const float* bs1 = Bp + (size_t)(kt + 64 + kq1*4) * ldb + n0 + nq0*4;
            #pragma unroll
            for (int j = 0; j < 4; ++j) { breg[0][j] = *(const f4*)(bs0 + j*ldb);
                                          breg[1][j] = *(const f4*)(bs1 + j*ldb); }
        }
        // compute: 2 k-steps of 32, 16 MFMA each
        #pragma unroll
        for (int s = 0; s < 2; ++s) {
            s16x8 a[4], b[4];
            const int kc = s*4 + fq;
            #pragma unroll
            for (int m = 0; m < 4; ++m) {
                int row = wm*64 + m*16 + fr;
                a[m] = *(const s16x8*)&As[row*64 + ((kc ^ swz(row)) << 3)];
            }
            #pragma unroll
            for (int n = 0; n < 4; ++n) {
                int col = wn*64 + n*16 + fr;
                b[n] = *(const s16x8*)&Bs[col*64 + ((kc ^ swz(col)) << 3)];
            }
            #pragma unroll
            for (int m = 0; m < 4; ++m)
                #pragma unroll
                for (int n = 0; n < 4; ++n)
                    acc[m][n] = __builtin_amdgcn_mfma_f32_16x16x32_bf16(
                        a[m], b[n], acc[m][n], 0, 0, 0);
        }
    }

    // epilogue: C/D layout col = lane&15, row = (lane>>4)*4 + reg  [m89]
    float bv[4];
    #pragma unroll
    for (int n = 0; n < 4; ++n) bv[n] = biasp[n0 + wn*64 + n*16 + fr];
    #pragma unroll
    for (int m = 0; m < 4; ++m) {
        #pragma unroll
        for (int rg = 0; rg < 4; ++rg) {
            int gr = m0 + wm*64 + m*16 + fq*4 + rg;
            if (gr >= nrows) continue;         // ragged tail guard
            size_t rowoff = (size_t)(rowbase + gr) * ldc;
            #pragma unroll
            for (int n = 0; n < 4; ++n) {
                int gc = n0 + wn*64 + n*16 + fr;
                float x = acc[m][n][rg];
                if (MODE == 1) {
                    x = gelu_exact(x + bv[n]);
                    ((unsigned short*)Cout)[rowoff + gc] = f2bf(x);
                } else {
                    float* pc = (float*)Cout + rowoff + gc;
                    x += first ? bv[n] : *pc;
                    *pc = x;
                }
            }
        }
    }
}

// ---------------- gating / routing (unchanged from round 3) ----------------
__global__ __launch_bounds__(256)
void gate_k(const float* __restrict__ r, const float* __restrict__ keys,
            int* __restrict__ topidx, float* __restrict__ gates)
{
    const int wave = threadIdx.x >> 6;
    const int lane = threadIdx.x & 63;
    const int t = blockIdx.x * 4 + wave;

    float rv[8];
    const float* rrow = r + (long)t * DIM;
    #pragma unroll
    for (int j = 0; j < 8; ++j) rv[j] = rrow[lane + j*64];

    float logit[NE];
    #pragma unroll
    for (int e = 0; e < NE; ++e) {
        const float* krow = keys + e * DIM;
        float s = 0.f;
        #pragma unroll
        for (int j = 0; j < 8; ++j) {
            float d = rv[j] - krow[lane + j*64];
            s = fmaf(d, d, s);
        }
        #pragma unroll
        for (int o = 32; o > 0; o >>= 1) s += __shfl_xor(s, o, 64);
        logit[e] = -sqrtf(fmaxf(s, 0.f));
    }
    int sel[TOPK]; float selv[TOPK];
    unsigned mask = 0;
    #pragma unroll
    for (int k = 0; k < TOPK; ++k) {           // strict > : lowest index wins ties
        float best = -INFINITY; int bi = 0;
        #pragma unroll
        for (int e = 0; e < NE; ++e) {
            if (mask & (1u << e)) continue;
            if (logit[e] > best) { best = logit[e]; bi = e; }
        }
        mask |= 1u << bi; sel[k] = bi; selv[k] = best;
    }
    float m = selv[0], se = 0.f, ex[TOPK];
    #pragma unroll
    for (int k = 0; k < TOPK; ++k) { ex[k] = expf(selv[k] - m); se += ex[k]; }
    if (lane == 0) {
        #pragma unroll
        for (int k = 0; k < TOPK; ++k) {
            topidx[t*TOPK + k] = sel[k];
            gates [t*TOPK + k] = ex[k] / se;
        }
    }
}

__global__ void count_k(const int* __restrict__ topidx, int base4, int n4,
                        int* __restrict__ counts)
{
    int i = blockIdx.x * blockDim.x + threadIdx.x;
    if (i < n4) atomicAdd(&counts[topidx[base4 + i]], 1);
}

__global__ void scan_jobs_k(const int* __restrict__ counts, int* __restrict__ offsets,
                            int* __restrict__ jobs, int* __restrict__ jobCount)
{
    int off = 0, nj = 0;
    for (int e = 0; e < NE; ++e) {
        offsets[e] = off;
        int n = counts[e];
        for (int m0 = 0; m0 < n; m0 += BM) { jobs[2*nj] = e; jobs[2*nj+1] = m0; ++nj; }
        off += n;
    }
    offsets[NE] = off;
    *jobCount = nj;
}

__global__ void assign_k(const int* __restrict__ topidx, int base4, int baseTok, int n4,
                         const int* __restrict__ offsets, int* __restrict__ cursors,
                         int* __restrict__ pair_token, int* __restrict__ token_slot)
{
    int i = blockIdx.x * blockDim.x + threadIdx.x;
    if (i >= n4) return;
    int tl = i >> 2;
    int e = topidx[base4 + i];
    int slot = offsets[e] + atomicAdd(&cursors[e], 1);
    pair_token[slot] = baseTok + tl;   // GLOBAL token id (h gather)
    token_slot[i] = slot;              // chunk-local slot (combine)
}

__global__ __launch_bounds__(128)
void combine_k(const float* __restrict__ pout, const float* __restrict__ gates,
               const int* __restrict__ token_slot, float* __restrict__ out,
               int baseTok, int add)
{
    const int tl = blockIdx.x;
    const int gt = baseTok + tl;
    const int d4 = threadIdx.x;
    float4 acc = add ? ((const float4*)out)[(long)gt*128 + d4]
                     : make_float4(0.f, 0.f, 0.f, 0.f);
    #pragma unroll
    for (int k = 0; k < TOPK; ++k) {
        int slot = token_slot[tl*TOPK + k];
        float g  = gates[(long)gt*TOPK + k];
        float4 p = ((const float4*)pout)[(long)slot*128 + d4];
        acc.x = fmaf(g, p.x, acc.x); acc.y = fmaf(g, p.y, acc.y);
        acc.z = fmaf(g, p.z, acc.z); acc.w = fmaf(g, p.w, acc.w);
    }
    ((float4*)out)[(long)gt*128 + d4] = acc;
}

extern "C" void kernel_launch(void* const* d_in, const int* in_sizes, int n_in,
                              void* d_out, int out_size, void* d_ws, size_t ws_size,
                              hipStream_t stream)
{
    const float* view[2]  = {(const float*)d_in[0], (const float*)d_in[1]};
    const float* proj_w   = (const float*)d_in[2];
    const float* proj_b   = (const float*)d_in[3];
    const float* router_w = (const float*)d_in[4];
    const float* keys     = (const float*)d_in[5];
    const float* w1       = (const float*)d_in[6];
    const float* b1       = (const float*)d_in[7];
    const float* w2       = (const float*)d_in[8];
    const float* b2       = (const float*)d_in[9];
    float* out = (float*)d_out;

    // ---- ws budget (floats): h32[2M] | hb16[1M eq] | chunkA[2048C] |
    //      chunkB[2048C] | gates[16K] | ints[~50K]
    const size_t hF  = (size_t)BT * DIM;         // 2,097,152
    const size_t hbF = hF / 2;                   // bf16 h, in float units
    const size_t metaF = (size_t)BT * TOPK;
    const size_t metaI = (size_t)BT * TOPK * 3 + 16 + 16 + 1 + (NE + 1) + 320;
    int C = 512;
    {
        const int cand[3] = {2048, 1024, 512};
        for (int ci = 0; ci < 3; ++ci) {
            size_t needF = hF + hbF + 2 * (size_t)2048 * cand[ci] + metaF + metaI;
            if (needF * 4 + (4u << 20) <= ws_size) { C = cand[ci]; break; }
        }
    }
    const int chunks = BT / C;
    const int mj = C / 32 + NE;          // max jobs per chunk

    float* h32 = (float*)d_ws;
    unsigned short* hb = (unsigned short*)(h32 + hF);
    float* chunkA = h32 + hF + hbF;                    // hid_c (bf16 space)
    float* chunkB = chunkA + (size_t)2048 * C;         // pout_c (f32)
    float* gates  = chunkB + (size_t)2048 * C;
    int* topidx     = (int*)(gates + metaF);
    int* token_slot = topidx + BT*TOPK;
    int* pair_token = token_slot + BT*TOPK;
    int* counts     = pair_token + BT*TOPK;  // 16 ints (memset with next 17)
    int* cursors    = counts + NE;           // 16
    int* jobCount   = cursors + NE;          // 1   -> 33 total memset
    int* offsets    = jobCount + 1;          // 17
    int* jobs       = offsets + NE + 1;      // 320

    float* r = chunkA;   // router logits alias (dead before hid writes; for
                         // C=512 spans chunkA+chunkB which is exactly 2M floats)

    const long sB1 = (long)DIM * HID;
    const long sB2 = (long)HID * DIM;

    for (int v = 0; v < NVIEW; ++v) {
        dim3 g0(BT/64, DIM/64);   // 64 x 8 = 512 blocks
        // h = x @ proj_w[v] + proj_b[v]   (dual-store fp32 + bf16)
        gemm0_k<<<g0, 256, 0, stream>>>(view[v], proj_w + (long)v*DIM*DIM,
                                        proj_b + v*DIM, h32, hb);
        // r = h @ router_w[v]             (fp32 only: gate exactness)
        gemm0_k<<<g0, 256, 0, stream>>>(h32, router_w + (long)v*DIM*DIM,
                                        nullptr, r, nullptr);
        gate_k<<<BT/4, 256, 0, stream>>>(r, keys, topidx, gates);

        for (int c = 0; c < chunks; ++c) {
            const int base4 = c * C * TOPK, baseTok = c * C, n4 = C * TOPK;
            (void)hipMemsetAsync(counts, 0, 33 * sizeof(int), stream);
            count_k<<<(n4 + 255)/256, 256, 0, stream>>>(topidx, base4, n4, counts);
            scan_jobs_k<<<1, 1, 0, stream>>>(counts, offsets, jobs, jobCount);
            assign_k<<<(n4 + 255)/256, 256, 0, stream>>>(topidx, base4, baseTok, n4,
                                                         offsets, cursors,
                                                         pair_token, token_slot);
            for (int s = 0; s < HSPLIT; ++s) {
                // hid = gelu(gather(hb) @ w1[e][:, s*HS:(s+1)*HS] + b1[e][s*HS:])
                moe_mfma_k<1><<<dim3(mj, HS/128), 256, 0, stream>>>(
                    hb, w1 + s*HS, b1 + s*HS, (void*)chunkA,
                    DIM, DIM, HID, HS, HID, sB1,
                    offsets, jobs, jobCount, pair_token, 0);
                // pout (=|+=) hid @ w2[e][s*HS:(s+1)*HS, :] (+ b2[e] on s==0)
                moe_mfma_k<2><<<dim3(mj, DIM/128), 256, 0, stream>>>(
                    (const unsigned short*)chunkA, w2 + (long)s*HS*DIM, b2,
                    (void*)chunkB,
                    HS, HS, DIM, DIM, DIM, sB2,
                    offsets, jobs, jobCount, nullptr, (s == 0) ? 1 : 0);
            }
            combine_k<<<C, 128, 0, stream>>>(chunkB, gates, token_slot, out,
                                             baseTok, v);
        }
    }
}

// Round 5
// 1103.296 us; speedup vs baseline: 3.5084x; 1.1386x over previous
//
#include <hip/hip_runtime.h>
#include <math.h>

// Problem constants
#define BT   4096
#define DIM  512
#define NE   16
#define TOPK 4
#define HID  2048
#define NVIEW 2
#define HSPLIT 4
#define HS   (HID/HSPLIT)   // 512
#define BMJ  128            // job row granularity

typedef float f4 __attribute__((ext_vector_type(4)));
typedef float f32x4 __attribute__((ext_vector_type(4)));
typedef short s16x8 __attribute__((ext_vector_type(8)));
typedef unsigned short u16x8 __attribute__((ext_vector_type(8)));
typedef unsigned short u16x4 __attribute__((ext_vector_type(4)));

__device__ __forceinline__ unsigned short f2bf(float f) {   // fp32 -> bf16 RNE
    unsigned u = __float_as_uint(f);
    unsigned r = u + 0x7FFFu + ((u >> 16) & 1u);
    return (unsigned short)(r >> 16);
}
__device__ __forceinline__ float gelu_exact(float x) {
    return 0.5f * x * (1.0f + erff(x * 0.70710678118654752f));
}
// 16B-chunk swizzle within a 128B LDS row (bijective per row).
__device__ __forceinline__ int swz(int r) { return (r ^ (r >> 3)) & 7; }

// async global->LDS, 16B per lane; LDS dest must be wave-uniform base.
__device__ __forceinline__ void gload16(const void* g, void* l) {
    __builtin_amdgcn_global_load_lds(
        (const __attribute__((address_space(1))) unsigned int*)g,
        (__attribute__((address_space(3))) unsigned int*)l, 16, 0, 0);
}

// ---------------- fp32 64x64 GEMM for proj/router (unchanged, passed) ------
__global__ __launch_bounds__(256)
void gemm0_k(const float* __restrict__ A, const float* __restrict__ B,
             const float* __restrict__ bias, float* __restrict__ C,
             unsigned short* __restrict__ bfout)
{
    const int m0 = blockIdx.x * 64, n0 = blockIdx.y * 64;
    __shared__ float As[16][64];
    __shared__ float Bs[16][64];
    const int tid = threadIdx.x;
    const int tx = tid & 15, ty = tid >> 4;
    const int ar = tid >> 2, ak = (tid & 3) * 4;
    const int bk = tid >> 4, bn = (tid & 15) * 4;
    const float* Ar = A + (size_t)(m0 + ar) * DIM;

    float acc[4][4] = {};
    for (int kt = 0; kt < DIM; kt += 16) {
        f4 av = *(const f4*)(Ar + kt + ak);
        f4 bv = *(const f4*)(B + (size_t)(kt + bk) * DIM + n0 + bn);
        __syncthreads();
        As[ak+0][ar] = av[0]; As[ak+1][ar] = av[1];
        As[ak+2][ar] = av[2]; As[ak+3][ar] = av[3];
        *(f4*)&Bs[bk][bn] = bv;
        __syncthreads();
        #pragma unroll
        for (int k = 0; k < 16; ++k) {
            f4 a = *(const f4*)&As[k][ty*4];
            f4 b = *(const f4*)&Bs[k][tx*4];
            #pragma unroll
            for (int i = 0; i < 4; ++i)
                #pragma unroll
                for (int j = 0; j < 4; ++j)
                    acc[i][j] = fmaf(a[i], b[j], acc[i][j]);
        }
    }
    #pragma unroll
    for (int i = 0; i < 4; ++i) {
        int gr = m0 + ty*4 + i;
        f4 v;
        #pragma unroll
        for (int j = 0; j < 4; ++j)
            v[j] = acc[i][j] + (bias ? bias[n0 + tx*4 + j] : 0.f);
        *(f4*)(C + (size_t)gr * DIM + n0 + tx*4) = v;
        if (bfout) {
            u16x4 w = { f2bf(v[0]), f2bf(v[1]), f2bf(v[2]), f2bf(v[3]) };
            *(u16x4*)&bfout[(size_t)gr * DIM + n0 + tx*4] = w;
        }
    }
}

// ------------- weight slice transpose+cast: [e][k][n] f32 -> [e][n][k] bf16 -
// slice is 512x512 per expert; grid (NE, 8, 8), 64x64 tiles.
__global__ __launch_bounds__(256)
void transpcast_k(const float* __restrict__ in, long e_stride, int ld_in,
                  unsigned short* __restrict__ outp)
{
    __shared__ float t[64][65];
    const int e = blockIdx.x;
    const int k0 = blockIdx.y * 64, n0 = blockIdx.z * 64;
    const float* src = in + (size_t)e * e_stride + (size_t)k0 * ld_in + n0;
    const int tid = threadIdx.x;
    {
        int rr = tid >> 4, c4 = (tid & 15) * 4;
        #pragma unroll
        for (int j = 0; j < 4; ++j) {
            f4 v = *(const f4*)(src + (size_t)(rr + j*16) * ld_in + c4);
            t[rr + j*16][c4+0] = v[0]; t[rr + j*16][c4+1] = v[1];
            t[rr + j*16][c4+2] = v[2]; t[rr + j*16][c4+3] = v[3];
        }
    }
    __syncthreads();
    {
        int rn = tid >> 3, k8 = (tid & 7) * 8;
        unsigned short* dst = outp + (size_t)e * (512*512);
        #pragma unroll
        for (int j = 0; j < 2; ++j) {
            int n = rn + j*32;
            u16x8 w;
            #pragma unroll
            for (int i2 = 0; i2 < 8; ++i2) w[i2] = f2bf(t[k8 + i2][n]);
            *(u16x8*)(dst + (size_t)(n0 + n)*512 + k0 + k8) = w;
        }
    }
}

// ---------------- bf16 MFMA expert GEMM, gload_lds + LDS double-buffer -----
// Both modes: [rows x 512] @ Bt[e][n][512]^T-ish -> 128x128 tile, BK=64.
// MODE 1: hid(bf16) = gelu(gather(hb) @ w1Ts + b1s);  MODE 2: pout f32 (=|+=).
template<int MODE>
__global__ __launch_bounds__(256, 2)
void moe_k(const unsigned short* __restrict__ Ab,
           const unsigned short* __restrict__ Bt,    // [e][n 512][k 512] bf16
           const float* __restrict__ biasb, void* __restrict__ Cout,
           int bias_ld,
           const int* __restrict__ offsets, const int* __restrict__ jobs,
           const int* __restrict__ jobCount, const int* __restrict__ pair_token,
           int first)
{
    const int job = blockIdx.x;
    if (job >= *jobCount) return;          // uniform exit before barriers
    const int e  = jobs[2*job];
    const int m0 = jobs[2*job+1];
    const int rowbase = offsets[e];
    const int nrows   = offsets[e+1] - rowbase;
    const int n0 = blockIdx.y * 128;
    const unsigned short* Bte = Bt + (size_t)e * (512*512);

    __shared__ unsigned short lds[4*128*64];   // 64 KB: A0,B0,A1,B1
    unsigned short* As0 = lds;
    unsigned short* Bs0 = lds + 8192;
    unsigned short* As1 = lds + 16384;
    unsigned short* Bs1 = lds + 24576;

    const int tid  = threadIdx.x;
    const int wid  = tid >> 6, lane = tid & 63;
    const int sub  = lane >> 3, cc = lane & 7;
    const int wm = wid >> 1, wn = wid & 1;      // 2x2 wave grid, 64x64 each
    const int fr = lane & 15, fq = lane >> 4;

    // staging source offsets (elements): LDS slot (r,cc) <- global chunk cc^swz(r)
    size_t aoff[4], boff[4];
    #pragma unroll
    for (int i = 0; i < 4; ++i) {
        int r = wid*32 + i*8 + sub;             // tile row / col 0..127
        int gr = m0 + r; if (gr >= nrows) gr = nrows - 1;   // clamp, store-guarded
        size_t arow = (MODE == 1) ? (size_t)pair_token[rowbase + gr]
                                  : (size_t)(rowbase + gr);
        aoff[i] = arow * 512 + (size_t)((cc ^ swz(r)) << 3);
        boff[i] = (size_t)(n0 + r) * 512 + (size_t)((cc ^ swz(r)) << 3);
    }

    f32x4 acc[4][4] = {};

    auto stage = [&](int kt, unsigned short* Aw, unsigned short* Bw) {
        #pragma unroll
        for (int i = 0; i < 4; ++i) {
            gload16((const char*)Ab  + ((aoff[i] + kt) << 1),
                    (char*)Aw + ((wid*4 + i) << 10));
            gload16((const char*)Bte + ((boff[i] + kt) << 1),
                    (char*)Bw + ((wid*4 + i) << 10));
        }
    };
    auto compute = [&](const unsigned short* Ar, const unsigned short* Br) {
        #pragma unroll
        for (int s2 = 0; s2 < 2; ++s2) {
            const int kc = s2*4 + fq;
            s16x8 a[4], b[4];
            #pragma unroll
            for (int m = 0; m < 4; ++m) {
                int row = wm*64 + m*16 + fr;
                a[m] = *(const s16x8*)&Ar[row*64 + ((kc ^ swz(row)) << 3)];
            }
            #pragma unroll
            for (int n = 0; n < 4; ++n) {
                int col = wn*64 + n*16 + fr;
                b[n] = *(const s16x8*)&Br[col*64 + ((kc ^ swz(col)) << 3)];
            }
            #pragma unroll
            for (int m = 0; m < 4; ++m)
                #pragma unroll
                for (int n = 0; n < 4; ++n)
                    acc[m][n] = __builtin_amdgcn_mfma_f32_16x16x32_bf16(
                        a[m], b[n], acc[m][n], 0, 0, 0);
        }
    };

    // pipeline: barrier drains PREVIOUS tile's loads, then next tile's loads
    // fly during compute (one __syncthreads per K-step, loads overlap MFMA).
    stage(0, As0, Bs0);
    #pragma unroll 1
    for (int it = 0; it < 8; it += 2) {
        __syncthreads();                         // tile it ready; WAR on buf1
        if (it + 1 < 8) stage((it+1)*64, As1, Bs1);
        compute(As0, Bs0);
        __syncthreads();                         // tile it+1 ready; WAR on buf0
        if (it + 2 < 8) stage((it+2)*64, As0, Bs0);
        compute(As1, Bs1);
    }

    // epilogue: C/D layout col=lane&15, row=(lane>>4)*4+reg  (round-4 verified)
    float bv[4];
    #pragma unroll
    for (int n = 0; n < 4; ++n)
        bv[n] = biasb[(size_t)e * bias_ld + n0 + wn*64 + n*16 + fr];
    #pragma unroll
    for (int m = 0; m < 4; ++m)
        #pragma unroll
        for (int rg = 0; rg < 4; ++rg) {
            int gr = m0 + wm*64 + m*16 + fq*4 + rg;
            if (gr >= nrows) continue;
            size_t rowoff = (size_t)(rowbase + gr) * 512;
            #pragma unroll
            for (int n = 0; n < 4; ++n) {
                int gc = n0 + wn*64 + n*16 + fr;
                float x = acc[m][n][rg];
                if (MODE == 1) {
                    x = gelu_exact(x + bv[n]);
                    ((unsigned short*)Cout)[rowoff + gc] = f2bf(x);
                } else {
                    float* pc = (float*)Cout + rowoff + gc;
                    *pc = x + (first ? bv[n] : *pc);
                }
            }
        }
}

// ---------------- gating (unchanged, verified) ------------------------------
__global__ __launch_bounds__(256)
void gate_k(const float* __restrict__ r, const float* __restrict__ keys,
            int* __restrict__ topidx, float* __restrict__ gates)
{
    const int wave = threadIdx.x >> 6;
    const int lane = threadIdx.x & 63;
    const int t = blockIdx.x * 4 + wave;

    float rv[8];
    const float* rrow = r + (long)t * DIM;
    #pragma unroll
    for (int j = 0; j < 8; ++j) rv[j] = rrow[lane + j*64];

    float logit[NE];
    #pragma unroll
    for (int e = 0; e < NE; ++e) {
        const float* krow = keys + e * DIM;
        float s = 0.f;
        #pragma unroll
        for (int j = 0; j < 8; ++j) {
            float d = rv[j] - krow[lane + j*64];
            s = fmaf(d, d, s);
        }
        #pragma unroll
        for (int o = 32; o > 0; o >>= 1) s += __shfl_xor(s, o, 64);
        logit[e] = -sqrtf(fmaxf(s, 0.f));
    }
    int sel[TOPK]; float selv[TOPK];
    unsigned mask = 0;
    #pragma unroll
    for (int k = 0; k < TOPK; ++k) {           // strict >: lowest index wins ties
        float best = -INFINITY; int bi = 0;
        #pragma unroll
        for (int e = 0; e < NE; ++e) {
            if (mask & (1u << e)) continue;
            if (logit[e] > best) { best = logit[e]; bi = e; }
        }
        mask |= 1u << bi; sel[k] = bi; selv[k] = best;
    }
    float m = selv[0], se = 0.f, ex[TOPK];
    #pragma unroll
    for (int k = 0; k < TOPK; ++k) { ex[k] = expf(selv[k] - m); se += ex[k]; }
    if (lane == 0) {
        #pragma unroll
        for (int k = 0; k < TOPK; ++k) {
            topidx[t*TOPK + k] = sel[k];
            gates [t*TOPK + k] = ex[k] / se;
        }
    }
}

// ----- fused per-chunk routing: histogram + scan + jobs + slot assign -------
// one block per chunk; slot permutation within an expert doesn't change any
// computed value (per-row math identical), so output stays bitwise-determin.
__global__ __launch_bounds__(256)
void route_k(const int* __restrict__ topidx, int C,
             int* __restrict__ offsets4, int* __restrict__ jobs4,
             int* __restrict__ jobCount4,
             int* __restrict__ pair_token, int* __restrict__ token_slot, int mj)
{
    const int chunk = blockIdx.x;
    const int n4 = C * TOPK, base4 = chunk * n4, baseTok = chunk * C;
    __shared__ int cnt[NE], cur[NE], off[NE+1];
    const int tid = threadIdx.x;
    if (tid < NE) { cnt[tid] = 0; cur[tid] = 0; }
    __syncthreads();
    for (int i = tid; i < n4; i += 256) atomicAdd(&cnt[topidx[base4 + i]], 1);
    __syncthreads();
    if (tid == 0) {
        int o = 0, nj = 0;
        int* jb = jobs4 + chunk * 2 * mj;
        for (int e = 0; e < NE; ++e) {
            off[e] = o;
            offsets4[chunk*(NE+1) + e] = o;
            for (int m0 = 0; m0 < cnt[e]; m0 += BMJ) {
                jb[2*nj] = e; jb[2*nj+1] = m0; ++nj;
            }
            o += cnt[e];
        }
        off[NE] = o;
        offsets4[chunk*(NE+1) + NE] = o;
        jobCount4[chunk] = nj;
    }
    __syncthreads();
    for (int i = tid; i < n4; i += 256) {
        int et = topidx[base4 + i];
        int slot = off[et] + atomicAdd(&cur[et], 1);
        pair_token[base4 + slot] = baseTok + (i >> 2);   // global token id
        token_slot[base4 + i] = slot;                    // chunk-local slot
    }
}

// out[baseTok+tl,:] (=|+=) sum_k gate * pout[slot,:]
__global__ __launch_bounds__(128)
void combine_k(const float* __restrict__ pout, const float* __restrict__ gates,
               const int* __restrict__ token_slot, float* __restrict__ out,
               int baseTok, int add)
{
    const int tl = blockIdx.x;
    const int gt = baseTok + tl;
    const int d4 = threadIdx.x;
    float4 acc = add ? ((const float4*)out)[(long)gt*128 + d4]
                     : make_float4(0.f, 0.f, 0.f, 0.f);
    #pragma unroll
    for (int k = 0; k < TOPK; ++k) {
        int slot = token_slot[tl*TOPK + k];
        float g  = gates[(long)gt*TOPK + k];
        float4 p = ((const float4*)pout)[(long)slot*128 + d4];
        acc.x = fmaf(g, p.x, acc.x); acc.y = fmaf(g, p.y, acc.y);
        acc.z = fmaf(g, p.z, acc.z); acc.w = fmaf(g, p.w, acc.w);
    }
    ((float4*)out)[(long)gt*128 + d4] = acc;
}

extern "C" void kernel_launch(void* const* d_in, const int* in_sizes, int n_in,
                              void* d_out, int out_size, void* d_ws, size_t ws_size,
                              hipStream_t stream)
{
    const float* view[2]  = {(const float*)d_in[0], (const float*)d_in[1]};
    const float* proj_w   = (const float*)d_in[2];
    const float* proj_b   = (const float*)d_in[3];
    const float* router_w = (const float*)d_in[4];
    const float* keys     = (const float*)d_in[5];
    const float* w1       = (const float*)d_in[6];
    const float* b1       = (const float*)d_in[7];
    const float* w2       = (const float*)d_in[8];
    const float* b2       = (const float*)d_in[9];
    float* out = (float*)d_out;

    const size_t MB = 1u << 20;
    // layout: [w1Ts 8MB | w2Ts 8MB]  (h32 8MB aliases w1Ts — dead before transposes)
    //         [hb 4MB][chunkA][chunkB][gates][ints]
    int C = 1024;
    {
        const int cand[3] = {4096, 2048, 1024};
        for (int ci = 0; ci < 3; ++ci) {
            size_t cA = (size_t)cand[ci] * TOPK * HS * 2;    // hid bf16
            size_t cB = (size_t)cand[ci] * TOPK * DIM * 4;   // pout f32
            size_t need = 16*MB + 4*MB + cA + cB + 512*1024;
            if (need + 1*MB <= ws_size) { C = cand[ci]; break; }
        }
    }
    const int chunks = BT / C;
    const int mj = C/32 + NE;    // max jobs per chunk

    char* base = (char*)d_ws;
    unsigned short* w1Ts = (unsigned short*)base;             // 8 MB
    unsigned short* w2Ts = (unsigned short*)(base + 8*MB);    // 8 MB
    float* h32 = (float*)base;                                // alias (8 MB)
    unsigned short* hb = (unsigned short*)(base + 16*MB);     // 4 MB
    unsigned short* chunkA = (unsigned short*)(base + 20*MB);
    const size_t cAB = (size_t)C * TOPK * HS * 2;
    float* chunkB = (float*)(base + 20*MB + cAB);
    float* gates  = (float*)((char*)chunkB + (size_t)C * TOPK * DIM * 4);
    int* topidx     = (int*)(gates + (size_t)BT*TOPK);
    int* token_slot = topidx + BT*TOPK;
    int* pair_token = token_slot + BT*TOPK;
    int* offsets4   = pair_token + BT*TOPK;     // chunks*(NE+1)
    int* jobCount4  = offsets4 + 4*(NE+1);      // chunks
    int* jobs4      = jobCount4 + 4;            // chunks*2*mj
    float* r = (float*)chunkA;   // 8 MB router logits; dead before hid writes

    for (int v = 0; v < NVIEW; ++v) {
        dim3 g0(BT/64, DIM/64);
        gemm0_k<<<g0, 256, 0, stream>>>(view[v], proj_w + (size_t)v*DIM*DIM,
                                        proj_b + v*DIM, h32, hb);
        gemm0_k<<<g0, 256, 0, stream>>>(h32, router_w + (size_t)v*DIM*DIM,
                                        nullptr, r, nullptr);
        gate_k<<<BT/4, 256, 0, stream>>>(r, keys, topidx, gates);
        route_k<<<chunks, 256, 0, stream>>>(topidx, C, offsets4, jobs4,
                                            jobCount4, pair_token, token_slot, mj);
        for (int c = 0; c < chunks; ++c) {
            const int b4 = c * C * TOPK;
            const int* off_c = offsets4 + c*(NE+1);
            const int* jb_c  = jobs4 + c*2*mj;
            const int* jc_c  = jobCount4 + c;
            for (int s = 0; s < HSPLIT; ++s) {
                // w1 slice [e][k 512][n = s*HS..] -> w1Ts[e][n][k] bf16
                transpcast_k<<<dim3(NE,8,8), 256, 0, stream>>>(
                    w1 + (size_t)s*HS, (long)DIM*HID, HID, w1Ts);
                // w2 slice [e][h = s*HS..][d]    -> w2Ts[e][d][h-local] bf16
                transpcast_k<<<dim3(NE,8,8), 256, 0, stream>>>(
                    w2 + (size_t)s*HS*DIM, (long)HID*DIM, DIM, w2Ts);
                moe_k<1><<<dim3(mj,4), 256, 0, stream>>>(
                    hb, w1Ts, b1 + s*HS, (void*)chunkA, HID,
                    off_c, jb_c, jc_c, pair_token + b4, 0);
                moe_k<2><<<dim3(mj,4), 256, 0, stream>>>(
                    chunkA, w2Ts, b2, (void*)chunkB, DIM,
                    off_c, jb_c, jc_c, nullptr, (s == 0) ? 1 : 0);
            }
            combine_k<<<C, 128, 0, stream>>>(chunkB, gates, token_slot + b4,
                                             out, c*C, v);
        }
    }
}